// Round 1
// baseline (28915.808 us; speedup 1.0000x reference)
//
#include <hip/hip_runtime.h>
#include <math.h>

#define S_  256
#define B_  64
#define E_  512
#define H_  512
#define G4_ 2048   // 4*H
#define NL_ 4

__device__ __forceinline__ float fsigmoid(float x) {
    return 1.0f / (1.0f + __expf(-x));
}
__device__ __forceinline__ float ftanh_(float x) {
    x = fminf(fmaxf(x, -15.0f), 15.0f);
    float e = __expf(2.0f * x);
    return (e - 1.0f) / (e + 1.0f);
}

// ---------------------------------------------------------------------------
// pre[t][g][b] = sum_k In[t*64+b][k] * Wi[g][k] + bias[g]
// In: [16384, 512] row-major.  Wi: [2048, 512] row-major.  pre: [256][2048][64]
// (pre stored g-major over b so the step kernel's per-gate reads are coalesced
// across the 64 batch lanes.)
// ---------------------------------------------------------------------------
#define BM_ 128
#define BN_ 128
#define BK_ 16

__global__ __launch_bounds__(256) void pre_gemm_k(
    const float* __restrict__ In,
    const float* __restrict__ Wi,
    const float* __restrict__ bias,
    float* __restrict__ pre)
{
    __shared__ float As[BK_][BM_ + 4];   // +4 pad keeps float4 alignment (132*4=528, 16|528)
    __shared__ float Bs[BK_][BN_ + 4];

    const int tid = threadIdx.x;
    const int bx  = blockIdx.x;          // 0..2047
    const int m0  = (bx >> 4) * BM_;     // 128 m-tiles
    const int n0  = (bx & 15) * BN_;     // 16 n-tiles
    const int tx  = tid & 15;
    const int ty  = tid >> 4;
    const int lr  = tid >> 2;            // 0..63
    const int lc  = (tid & 3) << 2;      // 0,4,8,12

    float acc[8][8];
#pragma unroll
    for (int i = 0; i < 8; ++i)
#pragma unroll
        for (int j = 0; j < 8; ++j) acc[i][j] = 0.0f;

    for (int k0 = 0; k0 < E_; k0 += BK_) {
        float4 a0 = *(const float4*)&In[(size_t)(m0 + lr) * E_ + k0 + lc];
        float4 a1 = *(const float4*)&In[(size_t)(m0 + lr + 64) * E_ + k0 + lc];
        float4 b0 = *(const float4*)&Wi[(size_t)(n0 + lr) * E_ + k0 + lc];
        float4 b1 = *(const float4*)&Wi[(size_t)(n0 + lr + 64) * E_ + k0 + lc];
        __syncthreads();
        As[lc + 0][lr] = a0.x; As[lc + 1][lr] = a0.y; As[lc + 2][lr] = a0.z; As[lc + 3][lr] = a0.w;
        As[lc + 0][lr + 64] = a1.x; As[lc + 1][lr + 64] = a1.y; As[lc + 2][lr + 64] = a1.z; As[lc + 3][lr + 64] = a1.w;
        Bs[lc + 0][lr] = b0.x; Bs[lc + 1][lr] = b0.y; Bs[lc + 2][lr] = b0.z; Bs[lc + 3][lr] = b0.w;
        Bs[lc + 0][lr + 64] = b1.x; Bs[lc + 1][lr + 64] = b1.y; Bs[lc + 2][lr + 64] = b1.z; Bs[lc + 3][lr + 64] = b1.w;
        __syncthreads();
#pragma unroll
        for (int kk = 0; kk < BK_; ++kk) {
            float4 av0 = *(const float4*)&As[kk][ty * 8];
            float4 av1 = *(const float4*)&As[kk][ty * 8 + 4];
            float4 bv0 = *(const float4*)&Bs[kk][tx * 8];
            float4 bv1 = *(const float4*)&Bs[kk][tx * 8 + 4];
            float a[8] = {av0.x, av0.y, av0.z, av0.w, av1.x, av1.y, av1.z, av1.w};
            float b[8] = {bv0.x, bv0.y, bv0.z, bv0.w, bv1.x, bv1.y, bv1.z, bv1.w};
#pragma unroll
            for (int i = 0; i < 8; ++i)
#pragma unroll
                for (int j = 0; j < 8; ++j)
                    acc[i][j] = fmaf(a[i], b[j], acc[i][j]);
        }
    }

#pragma unroll
    for (int i = 0; i < 8; ++i) {
        int m  = m0 + ty * 8 + i;
        int tt = m >> 6;
        int bb = m & 63;
#pragma unroll
        for (int j = 0; j < 8; ++j) {
            int n = n0 + tx * 8 + j;
            pre[((size_t)tt * G4_ + n) * B_ + bb] = acc[i][j] + bias[n];
        }
    }
}

// ---------------------------------------------------------------------------
// One timestep, BOTH directions (independent). Grid = 256 WGs x 256 threads.
//   wg>>7 = dir (0 fwd, 1 bwd), wg&127 = j-tile (4 j-columns each).
//   thread = (jl 0..3, b 0..63); each thread owns one (b, j): 4 gate dots K=512.
// h double-buffered by launch parity; c is RMW-private per (dir,b,j).
// Direction-sum fused: the later writer of a time slot does +=.
//   slot tf: fwd writes at launch tf, bwd at launch 255-tf -> exactly one of a
//   pair of launches has t<=127 (store), the other adds.
// ---------------------------------------------------------------------------
#define KC_ 128

__global__ __launch_bounds__(256) void lstm_step_k(
    const float* __restrict__ pre,    // [S][G4][B]
    const float* __restrict__ Wh,     // [2048][512]
    float* __restrict__ hbuf,         // [2 parity][2 dir][B][H]
    float* __restrict__ cbuf,         // [2 dir][B][H]
    float* __restrict__ outsum,       // [S][B][H]
    float* __restrict__ hfin,         // [2 dir][B][H]
    int t, int lastLayer)
{
    __shared__ float Hs[KC_][B_ + 1];   // transposed [k][b], pad -> conflict-free

    const int tid = threadIdx.x;
    const int dir = blockIdx.x >> 7;
    const int jt  = blockIdx.x & 127;
    const int b   = tid & 63;
    const int jl  = tid >> 6;
    const int j   = jt * 4 + jl;
    const int tf  = dir ? (S_ - 1 - t) : t;

    float z0 = pre[((size_t)tf * G4_ + (0 * H_ + j)) * B_ + b];
    float z1 = pre[((size_t)tf * G4_ + (1 * H_ + j)) * B_ + b];
    float z2 = pre[((size_t)tf * G4_ + (2 * H_ + j)) * B_ + b];
    float z3 = pre[((size_t)tf * G4_ + (3 * H_ + j)) * B_ + b];

    if (t > 0) {
        const float* hin = hbuf + ((size_t)(t & 1) * 2 + dir) * B_ * H_;
        const float* w0 = Wh + (size_t)(0 * H_ + j) * H_;
        const float* w1 = Wh + (size_t)(1 * H_ + j) * H_;
        const float* w2 = Wh + (size_t)(2 * H_ + j) * H_;
        const float* w3 = Wh + (size_t)(3 * H_ + j) * H_;
        for (int k0 = 0; k0 < H_; k0 += KC_) {
            __syncthreads();
            // stage h[b][k0..k0+KC) transposed into LDS
            const float* src = hin + (size_t)b * H_ + k0 + jl * 32;
#pragma unroll
            for (int v = 0; v < 8; ++v) {
                float4 hv = *(const float4*)(src + v * 4);
                int kk = jl * 32 + v * 4;
                Hs[kk + 0][b] = hv.x;
                Hs[kk + 1][b] = hv.y;
                Hs[kk + 2][b] = hv.z;
                Hs[kk + 3][b] = hv.w;
            }
            __syncthreads();
#pragma unroll 4
            for (int kk = 0; kk < KC_; kk += 4) {
                float4 wv0 = *(const float4*)(w0 + k0 + kk);   // wave-uniform -> L1 broadcast
                float4 wv1 = *(const float4*)(w1 + k0 + kk);
                float4 wv2 = *(const float4*)(w2 + k0 + kk);
                float4 wv3 = *(const float4*)(w3 + k0 + kk);
                float h0 = Hs[kk + 0][b];
                float h1 = Hs[kk + 1][b];
                float h2 = Hs[kk + 2][b];
                float h3 = Hs[kk + 3][b];
                z0 = fmaf(h0, wv0.x, z0); z0 = fmaf(h1, wv0.y, z0); z0 = fmaf(h2, wv0.z, z0); z0 = fmaf(h3, wv0.w, z0);
                z1 = fmaf(h0, wv1.x, z1); z1 = fmaf(h1, wv1.y, z1); z1 = fmaf(h2, wv1.z, z1); z1 = fmaf(h3, wv1.w, z1);
                z2 = fmaf(h0, wv2.x, z2); z2 = fmaf(h1, wv2.y, z2); z2 = fmaf(h2, wv2.z, z2); z2 = fmaf(h3, wv2.w, z2);
                z3 = fmaf(h0, wv3.x, z3); z3 = fmaf(h1, wv3.y, z3); z3 = fmaf(h2, wv3.z, z3); z3 = fmaf(h3, wv3.w, z3);
            }
        }
    }

    float c_old = (t > 0) ? cbuf[((size_t)dir * B_ + b) * H_ + j] : 0.0f;
    // gate order from reference split: i, f, o, g
    float si = fsigmoid(z0);
    float sf = fsigmoid(z1);
    float so = fsigmoid(z2);
    float tg = ftanh_(z3);
    float c  = fmaf(sf, c_old, si * tg);
    float h  = so * ftanh_(c);

    cbuf[((size_t)dir * B_ + b) * H_ + j] = c;
    hbuf[((size_t)(((t + 1) & 1) * 2 + dir)) * B_ * H_ + (size_t)b * H_ + j] = h;

    size_t oidx = ((size_t)tf * B_ + b) * H_ + j;
    if (t <= 127) outsum[oidx] = h;      // first writer of this slot
    else          outsum[oidx] += h;     // second writer (earlier launch stored)

    if (lastLayer && t == S_ - 1) {
        hfin[((size_t)dir * B_ + b) * H_ + j] = h;   // dir0: hf (t=255), dir1: hb (t=0)
    }
}

__global__ __launch_bounds__(256) void final_tail_k(
    const float* __restrict__ hfin, float* __restrict__ outTail)
{
    int i = blockIdx.x * 256 + threadIdx.x;   // 32768 elements
    outTail[i] = hfin[i] + hfin[(size_t)B_ * H_ + i];
}

// ---------------------------------------------------------------------------
// Workspace layout (floats):
//   pre  : S*G4*B        = 33,554,432   (128 MB)
//   buf0 : S*B*H         =  8,388,608   ( 32 MB)
//   buf1 : S*B*H         =  8,388,608   ( 32 MB)
//   hbuf : 2*2*B*H       =    131,072
//   cbuf : 2*B*H         =     65,536
//   hfin : 2*B*H         =     65,536
// total ~193 MB
// ---------------------------------------------------------------------------
extern "C" void kernel_launch(void* const* d_in, const int* in_sizes, int n_in,
                              void* d_out, int out_size, void* d_ws, size_t ws_size,
                              hipStream_t stream) {
    const float* x    = (const float*)d_in[0];
    const float* Wi   = (const float*)d_in[1];
    const float* Wh   = (const float*)d_in[2];
    const float* bias = (const float*)d_in[3];
    float* out = (float*)d_out;

    float* ws   = (float*)d_ws;
    float* pre  = ws;
    float* buf0 = pre  + (size_t)S_ * G4_ * B_;
    float* buf1 = buf0 + (size_t)S_ * B_ * H_;
    float* hbuf = buf1 + (size_t)S_ * B_ * H_;
    float* cbuf = hbuf + (size_t)4 * B_ * H_;
    float* hfin = cbuf + (size_t)2 * B_ * H_;

    const float* in_ptr = x;
    for (int l = 0; l < NL_; ++l) {
        pre_gemm_k<<<2048, 256, 0, stream>>>(in_ptr, Wi + (size_t)l * G4_ * E_,
                                             bias + (size_t)l * G4_, pre);
        float* outp = (l == 0) ? buf0 : (l == 1) ? buf1 : (l == 2) ? buf0 : out;
        const float* whl = Wh + (size_t)l * G4_ * H_;
        for (int t = 0; t < S_; ++t) {
            lstm_step_k<<<256, 256, 0, stream>>>(pre, whl, hbuf, cbuf, outp, hfin,
                                                 t, (l == NL_ - 1) ? 1 : 0);
        }
        in_ptr = outp;
    }
    final_tail_k<<<128, 256, 0, stream>>>(hfin, out + (size_t)S_ * B_ * H_);
}

// Round 2
// 19404.283 us; speedup vs baseline: 1.4902x; 1.4902x over previous
//
#include <hip/hip_runtime.h>
#include <math.h>

#define S_  256
#define B_  64
#define E_  512
#define H_  512
#define G4_ 2048   // 4*H
#define NL_ 4

__device__ __forceinline__ float fsigmoid(float x) {
    return 1.0f / (1.0f + __expf(-x));
}
__device__ __forceinline__ float ftanh_(float x) {
    x = fminf(fmaxf(x, -15.0f), 15.0f);
    float e = __expf(2.0f * x);
    return (e - 1.0f) / (e + 1.0f);
}

// ---------------------------------------------------------------------------
// pre[t][g][b] = sum_k In[t*64+b][k] * Wi[g][k] + bias[g]
// In: [16384, 512] row-major.  Wi: [2048, 512] row-major.  pre: [256][2048][64]
// ---------------------------------------------------------------------------
#define BM_ 128
#define BN_ 128
#define BK_ 16

__global__ __launch_bounds__(256) void pre_gemm_k(
    const float* __restrict__ In,
    const float* __restrict__ Wi,
    const float* __restrict__ bias,
    float* __restrict__ pre)
{
    __shared__ float As[BK_][BM_ + 4];
    __shared__ float Bs[BK_][BN_ + 4];

    const int tid = threadIdx.x;
    const int bx  = blockIdx.x;          // 0..2047
    const int m0  = (bx >> 4) * BM_;
    const int n0  = (bx & 15) * BN_;
    const int tx  = tid & 15;
    const int ty  = tid >> 4;
    const int lr  = tid >> 2;            // 0..63
    const int lc  = (tid & 3) << 2;      // 0,4,8,12

    float acc[8][8];
#pragma unroll
    for (int i = 0; i < 8; ++i)
#pragma unroll
        for (int j = 0; j < 8; ++j) acc[i][j] = 0.0f;

    for (int k0 = 0; k0 < E_; k0 += BK_) {
        float4 a0 = *(const float4*)&In[(size_t)(m0 + lr) * E_ + k0 + lc];
        float4 a1 = *(const float4*)&In[(size_t)(m0 + lr + 64) * E_ + k0 + lc];
        float4 b0 = *(const float4*)&Wi[(size_t)(n0 + lr) * E_ + k0 + lc];
        float4 b1 = *(const float4*)&Wi[(size_t)(n0 + lr + 64) * E_ + k0 + lc];
        __syncthreads();
        As[lc + 0][lr] = a0.x; As[lc + 1][lr] = a0.y; As[lc + 2][lr] = a0.z; As[lc + 3][lr] = a0.w;
        As[lc + 0][lr + 64] = a1.x; As[lc + 1][lr + 64] = a1.y; As[lc + 2][lr + 64] = a1.z; As[lc + 3][lr + 64] = a1.w;
        Bs[lc + 0][lr] = b0.x; Bs[lc + 1][lr] = b0.y; Bs[lc + 2][lr] = b0.z; Bs[lc + 3][lr] = b0.w;
        Bs[lc + 0][lr + 64] = b1.x; Bs[lc + 1][lr + 64] = b1.y; Bs[lc + 2][lr + 64] = b1.z; Bs[lc + 3][lr + 64] = b1.w;
        __syncthreads();
#pragma unroll
        for (int kk = 0; kk < BK_; ++kk) {
            float4 av0 = *(const float4*)&As[kk][ty * 8];
            float4 av1 = *(const float4*)&As[kk][ty * 8 + 4];
            float4 bv0 = *(const float4*)&Bs[kk][tx * 8];
            float4 bv1 = *(const float4*)&Bs[kk][tx * 8 + 4];
            float a[8] = {av0.x, av0.y, av0.z, av0.w, av1.x, av1.y, av1.z, av1.w};
            float b[8] = {bv0.x, bv0.y, bv0.z, bv0.w, bv1.x, bv1.y, bv1.z, bv1.w};
#pragma unroll
            for (int i = 0; i < 8; ++i)
#pragma unroll
                for (int j = 0; j < 8; ++j)
                    acc[i][j] = fmaf(a[i], b[j], acc[i][j]);
        }
    }

#pragma unroll
    for (int i = 0; i < 8; ++i) {
        int m  = m0 + ty * 8 + i;
        int tt = m >> 6;
        int bb = m & 63;
#pragma unroll
        for (int j = 0; j < 8; ++j) {
            int n = n0 + tx * 8 + j;
            pre[((size_t)tt * G4_ + n) * B_ + bb] = acc[i][j] + bias[n];
        }
    }
}

// ---------------------------------------------------------------------------
// One timestep, BOTH directions. Grid = 256 WGs x 256 threads.
//   wg>>7 = dir, wg&127 = jt; thread = (jl = tid>>6, b = tid&63); j = jt*4+jl.
// h kept in a transposed+interleaved global layout:
//   hT4[parity][dir][k4 = 0..127][b = 0..63][4]   (k = 4*k4 + e)
// so reads are one coalesced float4 per 4 k per lane; no LDS, no barriers.
// Weight rows are wave-uniform (j uniform per wave) -> readfirstlane forces
// the scalar-load path (weights ride the K$ instead of polluting L1).
// Direction-sum fused via store(t<=127)/add(t>=128) as before.
// ---------------------------------------------------------------------------
__global__ __launch_bounds__(256) void lstm_step_k(
    const float* __restrict__ pre,     // [S][G4][B]
    const float* __restrict__ Wh,      // [2048][512]
    float* __restrict__ hbufT,         // [2 parity][2 dir][H/4][B][4]
    float* __restrict__ cbuf,          // [2 dir][H][B]
    float* __restrict__ outsum,        // [S][B][H]
    float* __restrict__ hfin,          // [2 dir][H][B]
    int t, int lastLayer)
{
    const int tid = threadIdx.x;
    const int dir = blockIdx.x >> 7;
    const int jt  = blockIdx.x & 127;
    const int b   = tid & 63;
    const int jl  = tid >> 6;
    const int j   = jt * 4 + jl;
    const int j_u = __builtin_amdgcn_readfirstlane(j);   // wave-uniform
    const int tf  = dir ? (S_ - 1 - t) : t;

    float z0 = pre[((size_t)tf * G4_ + (0 * H_ + j)) * B_ + b];
    float z1 = pre[((size_t)tf * G4_ + (1 * H_ + j)) * B_ + b];
    float z2 = pre[((size_t)tf * G4_ + (2 * H_ + j)) * B_ + b];
    float z3 = pre[((size_t)tf * G4_ + (3 * H_ + j)) * B_ + b];

    if (t > 0) {
        const float4* h4 = (const float4*)(hbufT +
            ((size_t)((t & 1) * 2 + dir)) * (size_t)H_ * B_);
        const float* w0 = Wh + (size_t)(0 * H_ + j_u) * H_;
        const float* w1 = Wh + (size_t)(1 * H_ + j_u) * H_;
        const float* w2 = Wh + (size_t)(2 * H_ + j_u) * H_;
        const float* w3 = Wh + (size_t)(3 * H_ + j_u) * H_;
#pragma unroll 8
        for (int k4 = 0; k4 < H_ / 4; ++k4) {
            float4 hv = h4[(size_t)k4 * B_ + b];
            float4 a0 = *(const float4*)(w0 + k4 * 4);
            float4 a1 = *(const float4*)(w1 + k4 * 4);
            float4 a2 = *(const float4*)(w2 + k4 * 4);
            float4 a3 = *(const float4*)(w3 + k4 * 4);
            z0 = fmaf(hv.x, a0.x, z0); z0 = fmaf(hv.y, a0.y, z0);
            z0 = fmaf(hv.z, a0.z, z0); z0 = fmaf(hv.w, a0.w, z0);
            z1 = fmaf(hv.x, a1.x, z1); z1 = fmaf(hv.y, a1.y, z1);
            z1 = fmaf(hv.z, a1.z, z1); z1 = fmaf(hv.w, a1.w, z1);
            z2 = fmaf(hv.x, a2.x, z2); z2 = fmaf(hv.y, a2.y, z2);
            z2 = fmaf(hv.z, a2.z, z2); z2 = fmaf(hv.w, a2.w, z2);
            z3 = fmaf(hv.x, a3.x, z3); z3 = fmaf(hv.y, a3.y, z3);
            z3 = fmaf(hv.z, a3.z, z3); z3 = fmaf(hv.w, a3.w, z3);
        }
    }

    float c_old = (t > 0) ? cbuf[((size_t)dir * H_ + j) * B_ + b] : 0.0f;
    // gate order: i, f, o, g
    float si = fsigmoid(z0);
    float sf = fsigmoid(z1);
    float so = fsigmoid(z2);
    float tg = ftanh_(z3);
    float c  = fmaf(sf, c_old, si * tg);
    float h  = so * ftanh_(c);

    cbuf[((size_t)dir * H_ + j) * B_ + b] = c;

    // h write into transposed-interleaved buffer for next step's reads
    float* hout = hbufT + ((size_t)(((t + 1) & 1) * 2 + dir)) * (size_t)H_ * B_;
    hout[((size_t)(j >> 2) * B_ + b) * 4 + (j & 3)] = h;

    size_t oidx = ((size_t)tf * B_ + b) * H_ + j;
    if (t <= 127) outsum[oidx] = h;      // first writer of this slot
    else          outsum[oidx] += h;     // second writer adds

    if (lastLayer && t == S_ - 1) {
        hfin[((size_t)dir * H_ + j) * B_ + b] = h;
    }
}

__global__ __launch_bounds__(256) void final_tail_k(
    const float* __restrict__ hfinT, float* __restrict__ outTail)
{
    int i = blockIdx.x * 256 + threadIdx.x;   // 32768 = B*H, out layout [B][H]
    int b = i >> 9;
    int j = i & 511;
    outTail[i] = hfinT[(size_t)j * B_ + b] + hfinT[(size_t)(H_ + j) * B_ + b];
}

// ---------------------------------------------------------------------------
// Workspace layout (floats):
//   pre   : S*G4*B  = 33,554,432
//   buf0  : S*B*H   =  8,388,608
//   buf1  : S*B*H   =  8,388,608
//   hbufT : 2*2*H*B =    262,144   (parity x dir x H/4 x B x 4)
//   cbuf  : 2*H*B   =     65,536
//   hfin  : 2*H*B   =     65,536
// ---------------------------------------------------------------------------
extern "C" void kernel_launch(void* const* d_in, const int* in_sizes, int n_in,
                              void* d_out, int out_size, void* d_ws, size_t ws_size,
                              hipStream_t stream) {
    const float* x    = (const float*)d_in[0];
    const float* Wi   = (const float*)d_in[1];
    const float* Wh   = (const float*)d_in[2];
    const float* bias = (const float*)d_in[3];
    float* out = (float*)d_out;

    float* ws    = (float*)d_ws;
    float* pre   = ws;
    float* buf0  = pre   + (size_t)S_ * G4_ * B_;
    float* buf1  = buf0  + (size_t)S_ * B_ * H_;
    float* hbufT = buf1  + (size_t)S_ * B_ * H_;
    float* cbuf  = hbufT + (size_t)4 * H_ * B_;
    float* hfin  = cbuf  + (size_t)2 * H_ * B_;

    const float* in_ptr = x;
    for (int l = 0; l < NL_; ++l) {
        pre_gemm_k<<<2048, 256, 0, stream>>>(in_ptr, Wi + (size_t)l * G4_ * E_,
                                             bias + (size_t)l * G4_, pre);
        float* outp = (l == 0) ? buf0 : (l == 1) ? buf1 : (l == 2) ? buf0 : out;
        const float* whl = Wh + (size_t)l * G4_ * H_;
        for (int t = 0; t < S_; ++t) {
            lstm_step_k<<<256, 256, 0, stream>>>(pre, whl, hbufT, cbuf, outp, hfin,
                                                 t, (l == NL_ - 1) ? 1 : 0);
        }
        in_ptr = outp;
    }
    final_tail_k<<<128, 256, 0, stream>>>(hfin, out + (size_t)S_ * B_ * H_);
}